// Round 3
// baseline (58.351 us; speedup 1.0000x reference)
//
#include <hip/hip_runtime.h>
#include <hip/hip_bf16.h>

#define NE 9          // experts
#define NDIM 1024     // feature dim
#define BM 128
#define BN 128
#define BK 64
#define NT (NDIM / BK)   // 16 K-steps
#define MAX_SLOTS 40     // max sum of ceil(cnt_e/BM)

typedef __attribute__((ext_vector_type(8))) short bf16x8;
typedef __attribute__((ext_vector_type(4))) float f32x4;

__device__ __forceinline__ unsigned pack2_bf16(float a, float b) {
    __hip_bfloat162 h = __float22bfloat162_rn(float2{a, b});
    return *reinterpret_cast<unsigned*>(&h);
}

__device__ __forceinline__ void gload_lds16(const void* g, void* l) {
    __builtin_amdgcn_global_load_lds(
        (const __attribute__((address_space(1))) unsigned int*)g,
        (__attribute__((address_space(3))) unsigned int*)l, 16, 0, 0);
}

// ---------------- bucket samples by expert + build M-tile slot table ----------------
__global__ void bucket_kernel(const int* __restrict__ sidx,
                              int* __restrict__ perm,
                              int* __restrict__ offsets,
                              int* __restrict__ slot_e,
                              int* __restrict__ slot_m0,
                              int* __restrict__ nslots,
                              int nB) {
    __shared__ int cnt[NE];
    __shared__ int cur[NE];
    int t = threadIdx.x;
    if (t < NE) cnt[t] = 0;
    __syncthreads();
    for (int i = t; i < nB; i += blockDim.x) atomicAdd(&cnt[sidx[i]], 1);
    __syncthreads();
    if (t == 0) {
        int run = 0, s = 0;
        for (int e = 0; e < NE; ++e) {
            cur[e] = run; offsets[e] = run;
            for (int m0 = 0; m0 < cnt[e]; m0 += BM) {
                slot_e[s] = e; slot_m0[s] = m0; ++s;
            }
            run += cnt[e];
        }
        offsets[NE] = run;
        *nslots = s;
    }
    __syncthreads();
    for (int i = t; i < nB; i += blockDim.x) {
        int p = atomicAdd(&cur[sidx[i]], 1);
        perm[p] = i;
    }
}

// ---------------- prep: W f32 -> bf16, x gathered (perm order) f32 -> bf16 ----------
// Unit = 8 consecutive floats (32B read, 16B bf16 write).
__global__ __launch_bounds__(256)
void prep_kernel(const float* __restrict__ x,
                 const float* __restrict__ W,
                 const int* __restrict__ perm,
                 unsigned short* __restrict__ xb,
                 unsigned short* __restrict__ Wb,
                 int nB) {
    const int NW8 = NE * NDIM * NDIM / 8;   // W units
    const int NX8 = nB * (NDIM / 8);        // x units (128 per row)
    const int tot = NW8 + NX8;
    const int stride = gridDim.x * blockDim.x;
    for (int u = blockIdx.x * blockDim.x + threadIdx.x; u < tot; u += stride) {
        const float4* src;
        uint4* dst;
        if (u < NW8) {
            src = (const float4*)W + 2 * (size_t)u;
            dst = (uint4*)Wb + u;
        } else {
            int v = u - NW8;
            int row = v >> 7;        // NDIM/8 = 128 units per row
            int c8 = v & 127;
            src = (const float4*)(x + (size_t)perm[row] * NDIM + c8 * 8);
            dst = (uint4*)xb + (size_t)row * 128 + c8;
        }
        float4 a = src[0], b = src[1];
        uint4 o;
        o.x = pack2_bf16(a.x, a.y);
        o.y = pack2_bf16(a.z, a.w);
        o.z = pack2_bf16(b.x, b.y);
        o.w = pack2_bf16(b.z, b.w);
        *dst = o;
    }
}

// ---------------- bf16 grouped GEMM, m97 structure ----------------
// 256 threads = 4 waves in 2x2; each wave owns a 64x64 output sub-tile.
// A rows are contiguous in xb (already permuted); staging via global_load_lds x16B.
__global__ __launch_bounds__(256, 3)
void gemm_bf16_kernel(const unsigned short* __restrict__ xb,
                      const unsigned short* __restrict__ Wb,
                      const float* __restrict__ bias,
                      const int* __restrict__ perm,
                      const int* __restrict__ offsets,
                      const int* __restrict__ slot_e,
                      const int* __restrict__ slot_m0,
                      const int* __restrict__ nslots,
                      float* __restrict__ out) {
    // N-column-per-XCD mapping: XCD = b&7 holds one 128-wide N column of Wb
    // for ALL experts (2.36 MB) -> L2-resident for the whole kernel.
    const int b    = blockIdx.x;
    const int n    = b & 7;
    const int slot = b >> 3;
    if (slot >= *nslots) return;

    const int e   = slot_e[slot];
    const int m0  = slot_m0[slot];
    const int off = offsets[e];
    const int cnt = offsets[e + 1] - off;
    const int n0  = n * BN;

    __shared__ unsigned short As[BM][BK];   // 16 KB, linear (global_load_lds dest)
    __shared__ unsigned short Bs[BN][BK];   // 16 KB

    const int t    = threadIdx.x;
    const int wave = t >> 6;
    const int lane = t & 63;
    const int fr   = lane & 15;
    const int fq   = lane >> 4;
    const int wr   = (wave >> 1) * 64;
    const int wc   = (wave & 1) * 64;

    // staging addressing: load i covers LDS bytes [i*4096 + t*16); row = i*32 + t/8,
    // col = (t&7)*8 bf16. Source rows are contiguous (xb pre-permuted).
    const unsigned short* asrc =
        xb + ((size_t)(off + m0) + (t >> 3)) * NDIM + (t & 7) * 8;
    const unsigned short* bsrc =
        Wb + ((size_t)e * NDIM + n0 + (t >> 3)) * NDIM + (t & 7) * 8;
    unsigned short* adst = &As[0][0] + wave * 512;   // +i*2048; HW adds lane*16B
    unsigned short* bdst = &Bs[0][0] + wave * 512;

    f32x4 acc[4][4];
#pragma unroll
    for (int i = 0; i < 4; ++i)
#pragma unroll
        for (int j = 0; j < 4; ++j) acc[i][j] = (f32x4)(0.0f);

    for (int k0 = 0; k0 < NDIM; k0 += BK) {
#pragma unroll
        for (int i = 0; i < 4; ++i) {
            gload_lds16(asrc + (size_t)i * 32 * NDIM + k0, adst + i * 2048);
            gload_lds16(bsrc + (size_t)i * 32 * NDIM + k0, bdst + i * 2048);
        }
        __syncthreads();   // drains vmcnt -> staged tile visible

#pragma unroll
        for (int kk = 0; kk < BK; kk += 32) {
            bf16x8 af[4], bfv[4];
#pragma unroll
            for (int mf = 0; mf < 4; ++mf)
                af[mf] = *reinterpret_cast<const bf16x8*>(&As[wr + mf * 16 + fr][kk + fq * 8]);
#pragma unroll
            for (int nf = 0; nf < 4; ++nf)
                bfv[nf] = *reinterpret_cast<const bf16x8*>(&Bs[wc + nf * 16 + fr][kk + fq * 8]);
#pragma unroll
            for (int mf = 0; mf < 4; ++mf)
#pragma unroll
                for (int nf = 0; nf < 4; ++nf)
                    acc[mf][nf] = __builtin_amdgcn_mfma_f32_16x16x32_bf16(
                        af[mf], bfv[nf], acc[mf][nf], 0, 0, 0);
        }
        __syncthreads();   // protect LDS before next stage
    }

    // ---- epilogue: bias add + scatter store via perm ----
    float bl[4];
#pragma unroll
    for (int nf = 0; nf < 4; ++nf)
        bl[nf] = bias[e * NDIM + n0 + wc + nf * 16 + fr];

#pragma unroll
    for (int mf = 0; mf < 4; ++mf) {
#pragma unroll
        for (int j = 0; j < 4; ++j) {
            int lm = wr + mf * 16 + fq * 4 + j;
            if (m0 + lm < cnt) {
                int grow = perm[off + m0 + lm];
                float* orow = out + (size_t)grow * NDIM;
#pragma unroll
                for (int nf = 0; nf < 4; ++nf) {
                    int col = n0 + wc + nf * 16 + fr;
                    orow[col] = acc[mf][nf][j] + bl[nf];
                }
            }
        }
    }
}

// ---------------- fallback (round-2 kernel) if ws too small for bf16 copies -------
#define LDSS 72
__global__ __launch_bounds__(512, 4)
void session_gemm_fallback(const float* __restrict__ x,
                           const float* __restrict__ W,
                           const float* __restrict__ bias,
                           const int* __restrict__ perm,
                           const int* __restrict__ offsets,
                           const int* __restrict__ slot_e,
                           const int* __restrict__ slot_m0,
                           const int* __restrict__ nslots,
                           float* __restrict__ out) {
    const int b    = blockIdx.x;
    const int xcd  = b & 7;
    const int ord  = b >> 3;
    const int n    = ord & 7;
    const int sg   = ord >> 3;
    const int slot = xcd + 8 * sg;
    if (slot >= *nslots) return;

    const int e   = slot_e[slot];
    const int m0  = slot_m0[slot];
    const int off = offsets[e];
    const int cnt = offsets[e + 1] - off;
    const int n0  = n * BN;

    __shared__ unsigned short As[2][BM][LDSS];
    __shared__ unsigned short Bs[2][BN][LDSS];

    const int t = threadIdx.x;
    const int s_col = (t & 15) * 4;
    const int s_row = t >> 4;

    int arow[4];
#pragma unroll
    for (int it = 0; it < 4; ++it) {
        int lm = it * 32 + s_row;
        arow[it] = (m0 + lm < cnt) ? perm[off + m0 + lm] : -1;
    }
    const float* wbase = W + ((size_t)e * NDIM + (size_t)(n0 + s_row)) * NDIM + s_col;
    const float* xcol  = x + s_col;

    const int wave = t >> 6;
    const int wr   = (wave >> 2) * 64;
    const int wc   = (wave & 3) * 32;
    const int lane = t & 63;
    const int fr   = lane & 15;
    const int fq   = lane >> 4;

    f32x4 acc[4][2];
#pragma unroll
    for (int i = 0; i < 4; ++i)
#pragma unroll
        for (int j = 0; j < 2; ++j) acc[i][j] = (f32x4)(0.0f);

    float4 av[4], bv[4];

#define LD_REGS(K0)                                                                 \
    do {                                                                            \
        _Pragma("unroll")                                                           \
        for (int it = 0; it < 4; ++it) {                                            \
            av[it] = (arow[it] >= 0)                                                \
                ? *reinterpret_cast<const float4*>(xcol + (size_t)arow[it] * NDIM + (K0)) \
                : float4{0.f, 0.f, 0.f, 0.f};                                       \
            bv[it] = *reinterpret_cast<const float4*>(wbase + (size_t)it * 32 * NDIM + (K0)); \
        }                                                                           \
    } while (0)

#define WR_LDS(BUF)                                                                 \
    do {                                                                            \
        _Pragma("unroll")                                                           \
        for (int it = 0; it < 4; ++it) {                                            \
            uint2 pa; pa.x = pack2_bf16(av[it].x, av[it].y);                        \
            pa.y = pack2_bf16(av[it].z, av[it].w);                                  \
            *reinterpret_cast<uint2*>(&As[BUF][it * 32 + s_row][s_col]) = pa;       \
            uint2 pb; pb.x = pack2_bf16(bv[it].x, bv[it].y);                        \
            pb.y = pack2_bf16(bv[it].z, bv[it].w);                                  \
            *reinterpret_cast<uint2*>(&Bs[BUF][it * 32 + s_row][s_col]) = pb;       \
        }                                                                           \
    } while (0)

    LD_REGS(0);
    WR_LDS(0);
    LD_REGS(BK);
    __syncthreads();

    for (int tt = 0; tt < NT; ++tt) {
        const int curb = tt & 1;
        if (tt + 1 < NT) WR_LDS(curb ^ 1);
        if (tt + 2 < NT) LD_REGS((tt + 2) * BK);
#pragma unroll
        for (int kk = 0; kk < BK; kk += 32) {
            bf16x8 af[4], bfv[2];
#pragma unroll
            for (int mf = 0; mf < 4; ++mf)
                af[mf] = *reinterpret_cast<const bf16x8*>(&As[curb][wr + mf * 16 + fr][kk + fq * 8]);
#pragma unroll
            for (int nf = 0; nf < 2; ++nf)
                bfv[nf] = *reinterpret_cast<const bf16x8*>(&Bs[curb][wc + nf * 16 + fr][kk + fq * 8]);
#pragma unroll
            for (int mf = 0; mf < 4; ++mf)
#pragma unroll
                for (int nf = 0; nf < 2; ++nf)
                    acc[mf][nf] = __builtin_amdgcn_mfma_f32_16x16x32_bf16(
                        af[mf], bfv[nf], acc[mf][nf], 0, 0, 0);
        }
        __syncthreads();
    }

    float bl[2];
#pragma unroll
    for (int nf = 0; nf < 2; ++nf)
        bl[nf] = bias[e * NDIM + n0 + wc + nf * 16 + fr];

#pragma unroll
    for (int mf = 0; mf < 4; ++mf) {
#pragma unroll
        for (int j = 0; j < 4; ++j) {
            int lm = wr + mf * 16 + fq * 4 + j;
            if (m0 + lm < cnt) {
                int grow = perm[off + m0 + lm];
                float* orow = out + (size_t)grow * NDIM;
#pragma unroll
                for (int nf = 0; nf < 2; ++nf) {
                    int col = n0 + wc + nf * 16 + fr;
                    orow[col] = acc[mf][nf][j] + bl[nf];
                }
            }
        }
    }
#undef LD_REGS
#undef WR_LDS
}

extern "C" void kernel_launch(void* const* d_in, const int* in_sizes, int n_in,
                              void* d_out, int out_size, void* d_ws, size_t ws_size,
                              hipStream_t stream) {
    const float* x    = (const float*)d_in[0];
    const float* W    = (const float*)d_in[1];
    const float* bias = (const float*)d_in[2];
    const int*   sidx = (const int*)d_in[3];
    float*       out  = (float*)d_out;

    const int nB = in_sizes[3];   // 4096

    // ws layout
    char* wsb = (char*)d_ws;
    size_t p_off   = (size_t)nB * 4;
    size_t p_slote = p_off + 64;
    size_t p_slotm = p_slote + MAX_SLOTS * 4;
    size_t p_nslot = p_slotm + MAX_SLOTS * 4;
    size_t p_xb    = ((p_nslot + 4 + 511) / 512) * 512;
    size_t xb_bytes = (size_t)(nB + BM) * NDIM * 2;   // +BM rows of slack for tile overrun
    size_t p_wb    = p_xb + xb_bytes;
    size_t need    = p_wb + (size_t)NE * NDIM * NDIM * 2;

    int* perm    = (int*)(wsb + 0);
    int* offsets = (int*)(wsb + p_off);
    int* slot_e  = (int*)(wsb + p_slote);
    int* slot_m0 = (int*)(wsb + p_slotm);
    int* nslots  = (int*)(wsb + p_nslot);

    bucket_kernel<<<1, 256, 0, stream>>>(sidx, perm, offsets, slot_e, slot_m0,
                                         nslots, nB);

    if (ws_size >= need) {
        unsigned short* xb = (unsigned short*)(wsb + p_xb);
        unsigned short* Wb = (unsigned short*)(wsb + p_wb);

        prep_kernel<<<2048, 256, 0, stream>>>(x, W, perm, xb, Wb, nB);

        gemm_bf16_kernel<<<MAX_SLOTS * 8, 256, 0, stream>>>(
            xb, Wb, bias, perm, offsets, slot_e, slot_m0, nslots, out);
    } else {
        session_gemm_fallback<<<MAX_SLOTS * 8, 512, 0, stream>>>(
            x, W, bias, perm, offsets, slot_e, slot_m0, nslots, out);
    }
}

// Round 4
// 41.992 us; speedup vs baseline: 1.3896x; 1.3896x over previous
//
#include <hip/hip_runtime.h>
#include <hip/hip_bf16.h>

#define NE 9          // experts
#define NDIM 1024     // feature dim
#define BM 64         // M-tile (bf16 path)
#define BN 128        // N-tile
#define BK 64         // K-step
#define NT (NDIM / BK)   // 16
#define MAX_SLOTS 80     // sum ceil(cnt_e/64) <= 4096/64 + 9 = 73

typedef __attribute__((ext_vector_type(8))) short bf16x8;
typedef __attribute__((ext_vector_type(4))) float f32x4;

__device__ __forceinline__ unsigned pack2_bf16(float a, float b) {
    __hip_bfloat162 h = __float22bfloat162_rn(float2{a, b});
    return *reinterpret_cast<unsigned*>(&h);
}

__device__ __forceinline__ void gload_lds16(const void* g, void* l) {
    __builtin_amdgcn_global_load_lds(
        (const __attribute__((address_space(1))) unsigned int*)g,
        (__attribute__((address_space(3))) unsigned int*)l, 16, 0, 0);
}

// ---------------- fused: bucket (block 0) + W/x -> bf16 convert (blocks 1+) --------
// x converted in NATURAL order (no perm dependency) so conversion and bucketing
// run concurrently inside one dispatch; GEMM does the row gather itself.
__global__ __launch_bounds__(256)
void prep_kernel(const float* __restrict__ x, const float* __restrict__ W,
                 const int* __restrict__ sidx,
                 unsigned short* __restrict__ xb, unsigned short* __restrict__ Wb,
                 int* __restrict__ perm, int* __restrict__ offsets,
                 int* __restrict__ slot_e, int* __restrict__ slot_m0,
                 int* __restrict__ nslots, int nB) {
    if (blockIdx.x == 0) {
        __shared__ int cnt[NE];
        __shared__ int cur[NE];
        int t = threadIdx.x;
        if (t < NE) cnt[t] = 0;
        __syncthreads();
        for (int i = t; i < nB; i += 256) atomicAdd(&cnt[sidx[i]], 1);
        __syncthreads();
        if (t == 0) {
            int run = 0, s = 0;
            for (int e = 0; e < NE; ++e) {
                cur[e] = run; offsets[e] = run;
                for (int m0 = 0; m0 < cnt[e]; m0 += BM) {
                    slot_e[s] = e; slot_m0[s] = m0; ++s;
                }
                run += cnt[e];
            }
            offsets[NE] = run;
            *nslots = s;
        }
        __syncthreads();
        for (int i = t; i < nB; i += 256) {
            int p = atomicAdd(&cur[sidx[i]], 1);
            perm[p] = i;
        }
    } else {
        const int NW8 = NE * NDIM * (NDIM / 8);
        const int NX8 = nB * (NDIM / 8);
        const int tot = NW8 + NX8;
        const int stride = (gridDim.x - 1) * 256;
        for (int u = (blockIdx.x - 1) * 256 + threadIdx.x; u < tot; u += stride) {
            const float4* src;
            uint4* dst;
            if (u < NW8) {
                src = (const float4*)W + 2 * (size_t)u;
                dst = (uint4*)Wb + u;
            } else {
                size_t v = (size_t)(u - NW8);
                src = (const float4*)x + 2 * v;
                dst = (uint4*)xb + v;
            }
            float4 a = src[0], c = src[1];
            uint4 o;
            o.x = pack2_bf16(a.x, a.y);
            o.y = pack2_bf16(a.z, a.w);
            o.z = pack2_bf16(c.x, c.y);
            o.w = pack2_bf16(c.z, c.w);
            *dst = o;
        }
    }
}

// ---------------- bf16 grouped GEMM: dbuf + gload_lds + both-sides swizzle ---------
// 256 threads = 4 waves (2M x 2N); wave tile 32x64. ~584 active blocks, 3/CU.
__global__ __launch_bounds__(256, 3)
void gemm_bf16_kernel(const unsigned short* __restrict__ xb,
                      const unsigned short* __restrict__ Wb,
                      const float* __restrict__ bias,
                      const int* __restrict__ perm,
                      const int* __restrict__ offsets,
                      const int* __restrict__ slot_e,
                      const int* __restrict__ slot_m0,
                      const int* __restrict__ nslots,
                      float* __restrict__ out) {
    // balanced contiguous slot->XCD partition (bijective, device-side nslots)
    const int b    = blockIdx.x;
    const int xcd  = b & 7;
    const int j    = b >> 3;          // 0..79
    const int ns   = *nslots;
    const int q    = ns >> 3, r = ns & 7;
    const int mine = q + (xcd < r ? 1 : 0);
    const int ls   = j >> 3;          // local slot index on this XCD
    if (ls >= mine) return;
    const int slot = xcd * q + (xcd < r ? xcd : r) + ls;
    const int n    = j & 7;

    const int e   = slot_e[slot];
    const int m0  = slot_m0[slot];
    const int off = offsets[e];
    const int cnt = offsets[e + 1] - off;
    const int n0  = n * BN;

    // ushort-indexed LDS: A0@0 A1@4096 B0@8192 B1@16384, 48 KB total
    __shared__ __align__(16) unsigned short lds[24576];

    const int t    = threadIdx.x;
    const int wave = t >> 6;
    const int lane = t & 63;
    const int fr   = lane & 15;
    const int fq   = lane >> 4;
    const int wr   = (wave >> 1) * 32;   // wave M-origin
    const int wc   = (wave & 1) * 64;    // wave N-origin
    const int xr   = fr & 7;             // read-side swizzle key (== row&7)

    // staging: per-lane global source with PRE-SWIZZLED column; LDS dest linear
    const int srow = t >> 3;                       // 0..31 (row within 32-row group)
    const int scol = ((t & 7) ^ (srow & 7)) * 8;   // swizzled bf16 col in K-block
    int lm0 = m0 + srow;      if (lm0 >= cnt) lm0 = cnt - 1;   // clamp: garbage rows
    int lm1 = m0 + 32 + srow; if (lm1 >= cnt) lm1 = cnt - 1;   // masked at store
    const unsigned short* asrc0 = xb + (size_t)perm[off + lm0] * NDIM + scol;
    const unsigned short* asrc1 = xb + (size_t)perm[off + lm1] * NDIM + scol;
    const unsigned short* bsrc  = Wb + ((size_t)e * NDIM + n0 + srow) * NDIM + scol;

    const int adst = wave * 512;          // + buf*4096 + i*2048 (HW adds lane*16B)
    const int bdst = 8192 + wave * 512;   // + buf*8192 + i*2048

    f32x4 acc[2][4];
#pragma unroll
    for (int i = 0; i < 2; ++i)
#pragma unroll
        for (int k = 0; k < 4; ++k) acc[i][k] = (f32x4)(0.0f);

#define STAGE(BUF, K0)                                                         \
    do {                                                                       \
        gload_lds16(asrc0 + (K0), &lds[(BUF) * 4096 + adst]);                  \
        gload_lds16(asrc1 + (K0), &lds[(BUF) * 4096 + 2048 + adst]);           \
        _Pragma("unroll")                                                      \
        for (int i = 0; i < 4; ++i)                                            \
            gload_lds16(bsrc + (size_t)i * 32 * NDIM + (K0),                   \
                        &lds[(BUF) * 8192 + bdst + i * 2048]);                 \
    } while (0)

    STAGE(0, 0);
    __syncthreads();

    int buf = 0;
    for (int tt = 0; tt < NT; ++tt) {
        // issue next tile's loads first; they fly under this tile's compute
        if (tt + 1 < NT) STAGE(buf ^ 1, (tt + 1) * BK);

#pragma unroll
        for (int kk = 0; kk < 2; ++kk) {
            const int cs = ((kk * 4 + fq) ^ xr) * 8;   // swizzled read col (elems)
            bf16x8 af[2], bfv[4];
#pragma unroll
            for (int mf = 0; mf < 2; ++mf)
                af[mf] = *reinterpret_cast<const bf16x8*>(
                    &lds[buf * 4096 + (wr + mf * 16 + fr) * 64 + cs]);
#pragma unroll
            for (int nf = 0; nf < 4; ++nf)
                bfv[nf] = *reinterpret_cast<const bf16x8*>(
                    &lds[8192 + buf * 8192 + (wc + nf * 16 + fr) * 64 + cs]);
#pragma unroll
            for (int mf = 0; mf < 2; ++mf)
#pragma unroll
                for (int nf = 0; nf < 4; ++nf)
                    acc[mf][nf] = __builtin_amdgcn_mfma_f32_16x16x32_bf16(
                        af[mf], bfv[nf], acc[mf][nf], 0, 0, 0);
        }
        __syncthreads();   // drains this iter's stage loads + protects buf reuse
        buf ^= 1;
    }
#undef STAGE

    // ---- epilogue: bias add + scatter store via perm ----
    float bl[4];
#pragma unroll
    for (int nf = 0; nf < 4; ++nf)
        bl[nf] = bias[e * NDIM + n0 + wc + nf * 16 + fr];

#pragma unroll
    for (int mf = 0; mf < 2; ++mf) {
#pragma unroll
        for (int jr = 0; jr < 4; ++jr) {
            int lm = wr + mf * 16 + fq * 4 + jr;
            if (m0 + lm < cnt) {
                int grow = perm[off + m0 + lm];
                float* orow = out + (size_t)grow * NDIM;
#pragma unroll
                for (int nf = 0; nf < 4; ++nf)
                    orow[n0 + wc + nf * 16 + fr] = acc[mf][nf][jr] + bl[nf];
            }
        }
    }
}

// ================= fallback path (proven round-2 kernels) if ws too small =========
#define BMF 128
#define LDSS 72
#define MAX_SLOTS_F 40

__global__ void bucket_kernel_f(const int* __restrict__ sidx,
                                int* __restrict__ perm,
                                int* __restrict__ offsets,
                                int* __restrict__ slot_e,
                                int* __restrict__ slot_m0,
                                int* __restrict__ nslots,
                                int nB) {
    __shared__ int cnt[NE];
    __shared__ int cur[NE];
    int t = threadIdx.x;
    if (t < NE) cnt[t] = 0;
    __syncthreads();
    for (int i = t; i < nB; i += blockDim.x) atomicAdd(&cnt[sidx[i]], 1);
    __syncthreads();
    if (t == 0) {
        int run = 0, s = 0;
        for (int e = 0; e < NE; ++e) {
            cur[e] = run; offsets[e] = run;
            for (int m0 = 0; m0 < cnt[e]; m0 += BMF) {
                slot_e[s] = e; slot_m0[s] = m0; ++s;
            }
            run += cnt[e];
        }
        offsets[NE] = run;
        *nslots = s;
    }
    __syncthreads();
    for (int i = t; i < nB; i += blockDim.x) {
        int p = atomicAdd(&cur[sidx[i]], 1);
        perm[p] = i;
    }
}

__global__ __launch_bounds__(512, 4)
void session_gemm_fallback(const float* __restrict__ x,
                           const float* __restrict__ W,
                           const float* __restrict__ bias,
                           const int* __restrict__ perm,
                           const int* __restrict__ offsets,
                           const int* __restrict__ slot_e,
                           const int* __restrict__ slot_m0,
                           const int* __restrict__ nslots,
                           float* __restrict__ out) {
    const int b    = blockIdx.x;
    const int xcd  = b & 7;
    const int ord  = b >> 3;
    const int n    = ord & 7;
    const int sg   = ord >> 3;
    const int slot = xcd + 8 * sg;
    if (slot >= *nslots) return;

    const int e   = slot_e[slot];
    const int m0  = slot_m0[slot];
    const int off = offsets[e];
    const int cnt = offsets[e + 1] - off;
    const int n0  = n * BN;

    __shared__ unsigned short As[2][BMF][LDSS];
    __shared__ unsigned short Bs[2][BN][LDSS];

    const int t = threadIdx.x;
    const int s_col = (t & 15) * 4;
    const int s_row = t >> 4;

    int arow[4];
#pragma unroll
    for (int it = 0; it < 4; ++it) {
        int lm = it * 32 + s_row;
        arow[it] = (m0 + lm < cnt) ? perm[off + m0 + lm] : -1;
    }
    const float* wbase = W + ((size_t)e * NDIM + (size_t)(n0 + s_row)) * NDIM + s_col;
    const float* xcol  = x + s_col;

    const int wave = t >> 6;
    const int wr   = (wave >> 2) * 64;
    const int wc   = (wave & 3) * 32;
    const int lane = t & 63;
    const int fr   = lane & 15;
    const int fq   = lane >> 4;

    f32x4 acc[4][2];
#pragma unroll
    for (int i = 0; i < 4; ++i)
#pragma unroll
        for (int k = 0; k < 2; ++k) acc[i][k] = (f32x4)(0.0f);

    float4 av[4], bv[4];

#define LD_REGS(K0)                                                                 \
    do {                                                                            \
        _Pragma("unroll")                                                           \
        for (int it = 0; it < 4; ++it) {                                            \
            av[it] = (arow[it] >= 0)                                                \
                ? *reinterpret_cast<const float4*>(xcol + (size_t)arow[it] * NDIM + (K0)) \
                : float4{0.f, 0.f, 0.f, 0.f};                                       \
            bv[it] = *reinterpret_cast<const float4*>(wbase + (size_t)it * 32 * NDIM + (K0)); \
        }                                                                           \
    } while (0)

#define WR_LDS(BUF)                                                                 \
    do {                                                                            \
        _Pragma("unroll")                                                           \
        for (int it = 0; it < 4; ++it) {                                            \
            uint2 pa; pa.x = pack2_bf16(av[it].x, av[it].y);                        \
            pa.y = pack2_bf16(av[it].z, av[it].w);                                  \
            *reinterpret_cast<uint2*>(&As[BUF][it * 32 + s_row][s_col]) = pa;       \
            uint2 pb; pb.x = pack2_bf16(bv[it].x, bv[it].y);                        \
            pb.y = pack2_bf16(bv[it].z, bv[it].w);                                  \
            *reinterpret_cast<uint2*>(&Bs[BUF][it * 32 + s_row][s_col]) = pb;       \
        }                                                                           \
    } while (0)

    LD_REGS(0);
    WR_LDS(0);
    LD_REGS(BK);
    __syncthreads();

    for (int tt = 0; tt < NT; ++tt) {
        const int curb = tt & 1;
        if (tt + 1 < NT) WR_LDS(curb ^ 1);
        if (tt + 2 < NT) LD_REGS((tt + 2) * BK);
#pragma unroll
        for (int kk = 0; kk < BK; kk += 32) {
            bf16x8 af[4], bfv[2];
#pragma unroll
            for (int mf = 0; mf < 4; ++mf)
                af[mf] = *reinterpret_cast<const bf16x8*>(&As[curb][wr + mf * 16 + fr][kk + fq * 8]);
#pragma unroll
            for (int nf = 0; nf < 2; ++nf)
                bfv[nf] = *reinterpret_cast<const bf16x8*>(&Bs[curb][wc + nf * 16 + fr][kk + fq * 8]);
#pragma unroll
            for (int mf = 0; mf < 4; ++mf)
#pragma unroll
                for (int nf = 0; nf < 2; ++nf)
                    acc[mf][nf] = __builtin_amdgcn_mfma_f32_16x16x32_bf16(
                        af[mf], bfv[nf], acc[mf][nf], 0, 0, 0);
        }
        __syncthreads();
    }

    float bl[2];
#pragma unroll
    for (int nf = 0; nf < 2; ++nf)
        bl[nf] = bias[e * NDIM + n0 + wc + nf * 16 + fr];

#pragma unroll
    for (int mf = 0; mf < 4; ++mf) {
#pragma unroll
        for (int jr = 0; jr < 4; ++jr) {
            int lm = wr + mf * 16 + fq * 4 + jr;
            if (m0 + lm < cnt) {
                int grow = perm[off + m0 + lm];
                float* orow = out + (size_t)grow * NDIM;
#pragma unroll
                for (int nf = 0; nf < 2; ++nf) {
                    int col = n0 + wc + nf * 16 + fr;
                    orow[col] = acc[mf][nf][jr] + bl[nf];
                }
            }
        }
    }
#undef LD_REGS
#undef WR_LDS
}

extern "C" void kernel_launch(void* const* d_in, const int* in_sizes, int n_in,
                              void* d_out, int out_size, void* d_ws, size_t ws_size,
                              hipStream_t stream) {
    const float* x    = (const float*)d_in[0];
    const float* W    = (const float*)d_in[1];
    const float* bias = (const float*)d_in[2];
    const int*   sidx = (const int*)d_in[3];
    float*       out  = (float*)d_out;

    const int nB = in_sizes[3];   // 4096

    // ws layout
    char* wsb = (char*)d_ws;
    size_t p_off   = (size_t)nB * 4;
    size_t p_slote = p_off + 64;
    size_t p_slotm = p_slote + MAX_SLOTS * 4;
    size_t p_nslot = p_slotm + MAX_SLOTS * 4;
    size_t p_xb    = ((p_nslot + 4 + 511) / 512) * 512;
    size_t p_wb    = p_xb + (size_t)nB * NDIM * 2;
    size_t need    = p_wb + (size_t)NE * NDIM * NDIM * 2;

    int* perm    = (int*)(wsb + 0);
    int* offsets = (int*)(wsb + p_off);
    int* slot_e  = (int*)(wsb + p_slote);
    int* slot_m0 = (int*)(wsb + p_slotm);
    int* nslots  = (int*)(wsb + p_nslot);

    if (ws_size >= need) {
        unsigned short* xb = (unsigned short*)(wsb + p_xb);
        unsigned short* Wb = (unsigned short*)(wsb + p_wb);

        prep_kernel<<<1024, 256, 0, stream>>>(x, W, sidx, xb, Wb, perm, offsets,
                                              slot_e, slot_m0, nslots, nB);

        gemm_bf16_kernel<<<MAX_SLOTS * 8, 256, 0, stream>>>(
            xb, Wb, bias, perm, offsets, slot_e, slot_m0, nslots, out);
    } else {
        bucket_kernel_f<<<1, 256, 0, stream>>>(sidx, perm, offsets, slot_e,
                                               slot_m0, nslots, nB);
        session_gemm_fallback<<<MAX_SLOTS_F * 8, 512, 0, stream>>>(
            x, W, bias, perm, offsets, slot_e, slot_m0, nslots, out);
    }
}